// Round 2
// baseline (546.544 us; speedup 1.0000x reference)
//
#include <hip/hip_runtime.h>
#include <cstdint>

#define TT 8
#define OUT_S_OFF 33554432ull   // 8*4096*64*16

typedef __attribute__((ext_vector_type(8))) unsigned short ushort8v;

// ---------------- compile-time geometric algebra tables ----------------
// blade order matches reference _BLADES; BM_ = bitmask, IDXm_ = mask->index
constexpr int BM_[16]   = {0,1,2,4,8,3,5,9,6,10,12,7,11,13,14,15};
constexpr int IDXm_[16] = {0,1,2,5,3,6,8,11,4,7,9,12,10,13,14,15};
constexpr int G_[16]    = {0,1,1,1,1,2,2,2,2,2,2,3,3,3,3,4};
// e0-left-mult pairs: dst <- src (all +1): 1<-0, 5<-2, 6<-3, 7<-4, 11<-8, 12<-9, 13<-10, 15<-14
constexpr int SRC_[16]  = {0,0,2,3,4,2,3,4,8,9,10,8,9,10,14,14};
constexpr int HASP_[16] = {0,1,0,0,0,1,1,1,0,0,0,1,1,1,0,1};
constexpr int A2_[16]   = {0,5,0,0,0,6,6,6,0,0,0,7,7,7,0,8}; // 5+grade(src)
// wave-uniform pair-ness: waves 0,1 no-pair; waves 2,3 pair
constexpr int ORD_[16]  = {0,2,3,4, 8,9,10,14, 1,5,6,7, 11,12,13,15};

constexpr int pcnt_(int x){ int c=0; for(int b=0;b<8;b++) c += (x>>b)&1; return c; }
constexpr int par_(int A,int B){ int sw=0; for(int b=0;b<4;b++) if((B>>b)&1) sw += pcnt_(A>>(b+1)); return (sw&1)?-1:1; }
constexpr int sgnv_(int b){ return par_(BM_[b], 15 & ~BM_[b]); }

struct GTab { int cnt[16]; signed char jj[16][16]; signed char kk[16][16]; signed char ss[16][16]; };

constexpr GTab mk_cayley(){
  GTab t{};
  for(int j=0;j<16;j++) for(int k=0;k<16;k++){
    int A=BM_[j], B=BM_[k];
    if(A & B & 1) continue;             // e0*e0 = 0 (degenerate metric)
    int i = IDXm_[A^B]; int s = par_(A,B);
    int n = t.cnt[i]; t.jj[i][n]=(signed char)j; t.kk[i][n]=(signed char)k; t.ss[i][n]=(signed char)s; t.cnt[i]=n+1;
  }
  return t;
}
constexpr GTab mk_join(){
  GTab t{};
  for(int j=0;j<16;j++) for(int k=0;k<16;k++){
    int cj = 15 & ~BM_[j], ck = 15 & ~BM_[k];
    if(cj & ck) continue;               // wedge of complements zero
    int m  = cj | ck;
    int w  = par_(cj, ck);
    int mp = IDXm_[15 & ~m];
    int s  = sgnv_(j)*sgnv_(k)*w*sgnv_(mp);
    int n = t.cnt[mp]; t.jj[mp][n]=(signed char)j; t.kk[mp][n]=(signed char)k; t.ss[mp][n]=(signed char)s; t.cnt[mp]=n+1;
  }
  return t;
}

// ---------------- prepacked weights (device globals, rewritten every launch) ----------------
// WpIn[l][i][x][yb][p*4+yy]  l: 0=left 1=right 2=jleft 3=jright ; y = yb*4+yy (32)
__device__ unsigned short g_WpIn[4*16*64*8*8];     // 262144 bf16
// WpOut[i][x][yb][p*4+yy]  yb 0..15, y = yb*4+yy (64)
__device__ unsigned short g_WpOut[16*64*16*8];     // 131072 bf16
__device__ float g_s2mvT_in[4][64][32];            // [l][s][y]
__device__ float g_s2mvT_out[128][64];             // [s][y]
__device__ float g_mv2sT[64][64];                  // [c][y]
__device__ float g_s2sT[128][64];                  // [s][y]

__device__ __forceinline__ float bf2f(unsigned short u){ return __uint_as_float(((unsigned)u)<<16); }
__device__ __forceinline__ unsigned short f2bf(float f){
  unsigned u = __float_as_uint(f);
  return (unsigned short)((u + 0x7fffu + ((u>>16)&1u)) >> 16);
}

__global__ __launch_bounds__(256) void prepack(
    const float* wL, const float* wR, const float* wJL, const float* wJR, const float* wO,
    const float* s2L, const float* s2R, const float* s2JL, const float* s2JR,
    const float* s2O, const float* mv2s, const float* s2s)
{
  int idx = blockIdx.x*256 + threadIdx.x;
  if (idx < 262144) { // WpIn
    int q6 = idx & 63; int yy = q6 & 3, p = (q6>>2)&1, yb = q6>>3;
    int x = (idx>>6)&63, i = (idx>>12)&15, l = idx>>16;
    int y = yb*4 + yy;
    const float* w = (l==0)? wL : (l==1)? wR : (l==2)? wJL : wJR;
    float v = 0.f;
    if (p==0) v = w[(y*64+x)*9 + G_[i]];
    else if (HASP_[i]) v = w[(y*64+x)*9 + A2_[i]];
    g_WpIn[idx] = f2bf(v);
  }
  int i2 = idx - 262144;
  if (i2 >= 0 && i2 < 131072) { // WpOut
    int q3 = i2 & 7; int yy = q3 & 3, p = q3>>2;
    int yb = (i2>>3)&15, x = (i2>>7)&63, i = i2>>13;
    int y = yb*4 + yy;
    float v = 0.f;
    if (p==0) v = wO[(y*64+x)*9 + G_[i]];
    else if (HASP_[i]) v = wO[(y*64+x)*9 + A2_[i]];
    g_WpOut[i2] = f2bf(v);
  }
  int i3 = idx - 393216;
  if (i3 >= 0 && i3 < 8192) { // s2mvT_in [l][s][y]  (32x64 -> [s][y])
    int l = i3>>11, r = i3&2047; int s = r>>5, y = r&31;
    const float* src = (l==0)? s2L : (l==1)? s2R : (l==2)? s2JL : s2JR;
    g_s2mvT_in[l][s][y] = src[y*64 + s];
  }
  int i4 = idx - 401408;
  if (i4 >= 0 && i4 < 8192) { int s = i4>>6, y = i4&63; g_s2mvT_out[s][y] = s2O[y*128+s]; }
  int i5 = idx - 409600;
  if (i5 >= 0 && i5 < 4096) { int c = i5>>6, y = i5&63; g_mv2sT[c][y] = mv2s[y*64+c]; }
  int i6 = idx - 413696;
  if (i6 >= 0 && i6 < 8192) { int s = i6>>6, y = i6&63; g_s2sT[s][y] = s2s[y*128+s]; }
}

// ---------------- fused main kernel ----------------
__device__ __forceinline__ void load_mv_tile(int tid, const float* src, size_t tok0,
                                             unsigned short (*smv)[16][8])
{
  const float* base = src + tok0*1024;
  int x  = tid >> 2;
  int i0 = (tid & 3) * 4;
  #pragma unroll
  for (int k=0;k<8;k++){
    float4 v = *(const float4*)(base + (size_t)k*1024 + tid*4);
    smv[x][i0+0][k] = f2bf(v.x);
    smv[x][i0+1][k] = f2bf(v.y);
    smv[x][i0+2][k] = f2bf(v.z);
    smv[x][i0+3][k] = f2bf(v.w);
  }
}

__device__ __forceinline__ void do_linear_in(int tid, const unsigned short (*smv)[16][8],
                                             unsigned short (*dstA)[32][16], unsigned short (*dstB)[32][16],
                                             int lA, int lB)
{
  const int wave = tid>>6, lane = tid&63;
  const int i   = ORD_[wave*4 + (lane>>4)];
  const int lin = (lane>>3)&1;
  const int yb  = lane&7;
  const int l   = lin ? lB : lA;
  unsigned short (*dst)[32][16] = lin ? dstB : dstA;
  const int srci = SRC_[i];
  const bool hasp = HASP_[i] != 0;   // wave-uniform by ORD_
  float acc[4][8];
  #pragma unroll
  for(int q=0;q<4;q++)
    #pragma unroll
    for(int t=0;t<8;t++)
      acc[q][t]=0.f;
  const unsigned short* wp = &g_WpIn[(((l*16 + i)*64)*8 + yb)*8];
  if (hasp) {
    #pragma unroll 2
    for (int x=0;x<64;x++){
      ushort8v wv = *(const ushort8v*)(wp + x*64);
      ushort8v m0 = *(const ushort8v*)&smv[x][i][0];
      ushort8v m1 = *(const ushort8v*)&smv[x][srci][0];
      float w0f[4], w1f[4], m0f[8], m1f[8];
      #pragma unroll
      for(int q=0;q<4;q++){ w0f[q]=bf2f(wv[q]); w1f[q]=bf2f(wv[4+q]); }
      #pragma unroll
      for(int t=0;t<8;t++){ m0f[t]=bf2f(m0[t]); m1f[t]=bf2f(m1[t]); }
      #pragma unroll
      for(int q=0;q<4;q++)
        #pragma unroll
        for(int t=0;t<8;t++) acc[q][t] += w0f[q]*m0f[t] + w1f[q]*m1f[t];
    }
  } else {
    #pragma unroll 2
    for (int x=0;x<64;x++){
      ushort8v wv = *(const ushort8v*)(wp + x*64);
      ushort8v m0 = *(const ushort8v*)&smv[x][i][0];
      float w0f[4], m0f[8];
      #pragma unroll
      for(int q=0;q<4;q++) w0f[q]=bf2f(wv[q]);
      #pragma unroll
      for(int t=0;t<8;t++) m0f[t]=bf2f(m0[t]);
      #pragma unroll
      for(int q=0;q<4;q++)
        #pragma unroll
        for(int t=0;t<8;t++) acc[q][t] += w0f[q]*m0f[t];
    }
  }
  #pragma unroll
  for(int q=0;q<4;q++)
    #pragma unroll
    for(int t=0;t<8;t++) dst[t][yb*4+q][i] = f2bf(acc[q][t]);
}

__global__ __launch_bounds__(256, 3) void fused(
    const float* __restrict__ mv1, const float* __restrict__ mv2,
    const float* __restrict__ sc1, const float* __restrict__ sc2,
    const float* __restrict__ refmv, const float* __restrict__ bias,
    float* __restrict__ out)
{
  __shared__ __align__(16) unsigned short s_mv[64][16][8];   // mv tile; later hidden[ch][i][t]
  __shared__ __align__(16) unsigned short s_L [8][32][16];
  __shared__ __align__(16) unsigned short s_R [8][32][16];
  __shared__ __align__(16) unsigned short s_JL[8][32][16];
  __shared__ __align__(16) unsigned short s_JR[8][32][16];
  __shared__ __align__(16) unsigned short s_scT[128][8];     // s_cat transposed, bf16
  __shared__ float s_ref[8];
  __shared__ float s_add0[8][64];

  const int tid = threadIdx.x;
  const size_t tok0 = (size_t)blockIdx.x * TT;

  // ---- P0: scalars + ref + mv1 tile ----
  #pragma unroll
  for (int k=0;k<4;k++){
    int idx = tid + k*256;          // 0..1023
    int t = idx >> 7, s = idx & 127;
    float v = (s<64) ? sc1[(tok0+t)*64 + s] : sc2[(tok0+t)*64 + (s-64)];
    s_scT[s][t] = f2bf(v);
  }
  if (tid < 8) s_ref[tid] = refmv[(tok0+tid)*16 + 15];
  load_mv_tile(tid, mv1, tok0, s_mv);
  __syncthreads();

  // ---- P1: left / jleft ----
  do_linear_in(tid, s_mv, s_L, s_JL, 0, 2);
  __syncthreads();

  // ---- P2: mv2 tile ----
  load_mv_tile(tid, mv2, tok0, s_mv);
  __syncthreads();

  // ---- P3: right / jright ----
  do_linear_in(tid, s_mv, s_R, s_JR, 1, 3);
  __syncthreads();

  // ---- P3.5: scalar->mv adds into component 0 of L/R/JL/JR ----
  {
    int y = tid & 31, t = tid >> 5;
    #pragma unroll
    for (int l=0;l<4;l++){
      const float* wT = &g_s2mvT_in[l][0][0];
      int base = (l==1||l==3) ? 64 : 0;
      float v = 0.f;
      for (int s=0;s<64;s++) v += wT[s*32+y] * bf2f(s_scT[base+s][t]);
      unsigned short* d = (l==0)? &s_L[t][y][0] : (l==1)? &s_R[t][y][0]
                        : (l==2)? &s_JL[t][y][0] : &s_JR[t][y][0];
      *d = f2bf(bf2f(*d) + v);
    }
  }
  __syncthreads();

  // ---- P4: geometric product + join -> hidden (overlays s_mv) ----
  {
    const int c = tid & 31, t = tid >> 5;
    float Lf[16], Rf[16], JLf[16], JRf[16];
    {
      ushort8v a0 = *(const ushort8v*)&s_L[t][c][0];  ushort8v a1 = *(const ushort8v*)&s_L[t][c][8];
      ushort8v b0 = *(const ushort8v*)&s_R[t][c][0];  ushort8v b1 = *(const ushort8v*)&s_R[t][c][8];
      ushort8v c0 = *(const ushort8v*)&s_JL[t][c][0]; ushort8v c1 = *(const ushort8v*)&s_JL[t][c][8];
      ushort8v d0 = *(const ushort8v*)&s_JR[t][c][0]; ushort8v d1 = *(const ushort8v*)&s_JR[t][c][8];
      #pragma unroll
      for(int q=0;q<8;q++){
        Lf[q]=bf2f(a0[q]);  Lf[8+q]=bf2f(a1[q]);
        Rf[q]=bf2f(b0[q]);  Rf[8+q]=bf2f(b1[q]);
        JLf[q]=bf2f(c0[q]); JLf[8+q]=bf2f(c1[q]);
        JRf[q]=bf2f(d0[q]); JRf[8+q]=bf2f(d1[q]);
      }
    }
    constexpr GTab CAY = mk_cayley();
    constexpr GTab JNT = mk_join();
    float rv = s_ref[t];
    #pragma unroll
    for (int i=0;i<16;i++){
      float a = 0.f;
      #pragma unroll
      for (int e=0;e<CAY.cnt[i];e++){
        float p = Lf[(int)CAY.jj[i][e]] * Rf[(int)CAY.kk[i][e]];
        a = (CAY.ss[i][e] > 0) ? (a + p) : (a - p);
      }
      float b = 0.f;
      #pragma unroll
      for (int e=0;e<JNT.cnt[i];e++){
        float p = JLf[(int)JNT.jj[i][e]] * JRf[(int)JNT.kk[i][e]];
        b = (JNT.ss[i][e] > 0) ? (b + p) : (b - p);
      }
      s_mv[c][i][t]      = f2bf(a);
      s_mv[c+32][i][t]   = f2bf(b * rv);
    }
  }
  __syncthreads();

  // ---- P5: scalar output head + s2mv_out contribution ----
  {
    int y = tid & 63, th = tid >> 6;
    #pragma unroll
    for (int rep=0;rep<2;rep++){
      int t = th + rep*4;
      float v = bias[y];
      for (int c=0;c<64;c++) v += g_mv2sT[c][y] * bf2f(s_mv[c][0][t]);
      float a0 = 0.f;
      for (int s=0;s<128;s++){
        float sv = bf2f(s_scT[s][t]);
        v  += g_s2sT[s][y]    * sv;
        a0 += g_s2mvT_out[s][y] * sv;
      }
      out[OUT_S_OFF + (tok0+t)*64 + y] = v;
      s_add0[t][y] = a0;
    }
  }
  __syncthreads();

  // ---- P6: output equi-linear ----
  {
    const int wave = tid>>6, lane = tid&63;
    const int i  = ORD_[wave*4 + (lane>>4)];
    const int yb = lane & 15;
    const int srci = SRC_[i];
    const bool hasp = HASP_[i] != 0;
    float acc[4][8];
    #pragma unroll
    for(int q=0;q<4;q++)
      #pragma unroll
      for(int t=0;t<8;t++)
        acc[q][t]=0.f;
    const unsigned short* wp = &g_WpOut[((i*64)*16 + yb)*8];
    if (hasp) {
      #pragma unroll 2
      for (int x=0;x<64;x++){
        ushort8v wv = *(const ushort8v*)(wp + x*128);
        ushort8v m0 = *(const ushort8v*)&s_mv[x][i][0];
        ushort8v m1 = *(const ushort8v*)&s_mv[x][srci][0];
        float w0f[4], w1f[4], m0f[8], m1f[8];
        #pragma unroll
        for(int q=0;q<4;q++){ w0f[q]=bf2f(wv[q]); w1f[q]=bf2f(wv[4+q]); }
        #pragma unroll
        for(int t=0;t<8;t++){ m0f[t]=bf2f(m0[t]); m1f[t]=bf2f(m1[t]); }
        #pragma unroll
        for(int q=0;q<4;q++)
          #pragma unroll
          for(int t=0;t<8;t++) acc[q][t] += w0f[q]*m0f[t] + w1f[q]*m1f[t];
      }
    } else {
      #pragma unroll 2
      for (int x=0;x<64;x++){
        ushort8v wv = *(const ushort8v*)(wp + x*128);
        ushort8v m0 = *(const ushort8v*)&s_mv[x][i][0];
        float w0f[4], m0f[8];
        #pragma unroll
        for(int q=0;q<4;q++) w0f[q]=bf2f(wv[q]);
        #pragma unroll
        for(int t=0;t<8;t++) m0f[t]=bf2f(m0[t]);
        #pragma unroll
        for(int q=0;q<4;q++)
          #pragma unroll
          for(int t=0;t<8;t++) acc[q][t] += w0f[q]*m0f[t];
      }
    }
    #pragma unroll
    for(int q=0;q<4;q++){
      int y = yb*4+q;
      #pragma unroll
      for(int t=0;t<8;t++){
        float v = acc[q][t];
        if (i==0) v += s_add0[t][y];
        out[(tok0+t)*1024 + y*16 + i] = v;
      }
    }
  }
}

extern "C" void kernel_launch(void* const* d_in, const int* in_sizes, int n_in,
                              void* d_out, int out_size, void* d_ws, size_t ws_size,
                              hipStream_t stream) {
  const float* mv1   = (const float*)d_in[0];
  const float* mv2   = (const float*)d_in[1];
  const float* sc1   = (const float*)d_in[2];
  const float* sc2   = (const float*)d_in[3];
  const float* refmv = (const float*)d_in[4];
  const float* wL    = (const float*)d_in[5];
  const float* s2L   = (const float*)d_in[6];
  const float* wR    = (const float*)d_in[7];
  const float* s2R   = (const float*)d_in[8];
  const float* wJL   = (const float*)d_in[9];
  const float* s2JL  = (const float*)d_in[10];
  const float* wJR   = (const float*)d_in[11];
  const float* s2JR  = (const float*)d_in[12];
  const float* wO    = (const float*)d_in[13];
  const float* s2O   = (const float*)d_in[14];
  const float* mv2s  = (const float*)d_in[15];
  const float* s2s   = (const float*)d_in[16];
  const float* bias  = (const float*)d_in[17];
  float* out = (float*)d_out;

  prepack<<<1648, 256, 0, stream>>>(wL,wR,wJL,wJR,wO, s2L,s2R,s2JL,s2JR, s2O, mv2s, s2s);
  fused<<<4096, 256, 0, stream>>>(mv1, mv2, sc1, sc2, refmv, bias, out);
}

// Round 3
// 158.506 us; speedup vs baseline: 3.4481x; 3.4481x over previous
//
#include <hip/hip_runtime.h>
#include <cstdint>

#define OUT_S_OFF 33554432ull   // 8*4096*64*16

typedef short s16x8 __attribute__((ext_vector_type(8)));
typedef float f32x4 __attribute__((ext_vector_type(4)));

// ---------------- compile-time geometric algebra tables ----------------
constexpr int BM_[16]   = {0,1,2,4,8,3,5,9,6,10,12,7,11,13,14,15};
constexpr int IDXm_[16] = {0,1,2,5,3,6,8,11,4,7,9,12,10,13,14,15};
constexpr int G_[16]    = {0,1,1,1,1,2,2,2,2,2,2,3,3,3,3,4};
constexpr int SRC_[16]  = {0,0,2,3,4,2,3,4,8,9,10,8,9,10,14,14};
constexpr int HASP_[16] = {0,1,0,0,0,1,1,1,0,0,0,1,1,1,0,1};
constexpr int A2_[16]   = {0,5,0,0,0,6,6,6,0,0,0,7,7,7,0,8};

constexpr int pcnt_(int x){ int c=0; for(int b=0;b<8;b++) c += (x>>b)&1; return c; }
constexpr int par_(int A,int B){ int sw=0; for(int b=0;b<4;b++) if((B>>b)&1) sw += pcnt_(A>>(b+1)); return (sw&1)?-1:1; }
constexpr int sgnv_(int b){ return par_(BM_[b], 15 & ~BM_[b]); }

struct GTab { int cnt[16]; signed char jj[16][16]; signed char kk[16][16]; signed char ss[16][16]; };

constexpr GTab mk_cayley(){
  GTab t{};
  for(int j=0;j<16;j++) for(int k=0;k<16;k++){
    int A=BM_[j], B=BM_[k];
    if(A & B & 1) continue;
    int i = IDXm_[A^B]; int s = par_(A,B);
    int n = t.cnt[i]; t.jj[i][n]=(signed char)j; t.kk[i][n]=(signed char)k; t.ss[i][n]=(signed char)s; t.cnt[i]=n+1;
  }
  return t;
}
constexpr GTab mk_join(){
  GTab t{};
  for(int j=0;j<16;j++) for(int k=0;k<16;k++){
    int cj = 15 & ~BM_[j], ck = 15 & ~BM_[k];
    if(cj & ck) continue;
    int m  = cj | ck;
    int w  = par_(cj, ck);
    int mp = IDXm_[15 & ~m];
    int s  = sgnv_(j)*sgnv_(k)*w*sgnv_(mp);
    int n = t.cnt[mp]; t.jj[mp][n]=(signed char)j; t.kk[mp][n]=(signed char)k; t.ss[mp][n]=(signed char)s; t.cnt[mp]=n+1;
  }
  return t;
}

__device__ __forceinline__ unsigned short f2bf(float f){
  unsigned u = __float_as_uint(f);
  return (unsigned short)((u + 0x7fffu + ((u>>16)&1u)) >> 16);
}
__device__ __forceinline__ unsigned int pack2(float a, float b){
  return (unsigned int)f2bf(a) | ((unsigned int)f2bf(b) << 16);
}

// ---------------- prepacked weight fragments (B-operand order) ----------------
// element (lane,j): y = base + (lane&15); k = (lane>>4)*8 + j  (k within 32-wide step)
__device__ unsigned short g_WinB [4*16*4*2*512];  // [m][i][s(4)][h(2)][512]
__device__ unsigned short g_WoutB[16*6*4*512];    // [i][s(6)][nt(4)][512]
__device__ unsigned short g_WsB  [6*4*512];       // [s(6)][nt(4)][512]

__global__ __launch_bounds__(256) void prepack(
    const float* wL, const float* wR, const float* wJL, const float* wJR, const float* wO,
    const float* s2L, const float* s2R, const float* s2JL, const float* s2JR,
    const float* s2O, const float* mv2s, const float* s2s)
{
  int idx = blockIdx.x*256 + threadIdx.x;
  if (idx < 262144) {                       // g_WinB
    int j = idx&7, l=(idx>>3)&63, h=(idx>>9)&1, s=(idx>>10)&3, i=(idx>>12)&15, m=idx>>16;
    int y = h*16 + (l&15), k = ((l>>4)&3)*8 + j;
    const float* w  = (m==0)?wL:(m==1)?wR:(m==2)?wJL:wJR;
    const float* s2 = (m==0)?s2L:(m==1)?s2R:(m==2)?s2JL:s2JR;
    float v = 0.f;
    if (s < 2)            v = w[(y*64 + s*32 + k)*9 + G_[i]];
    else if (HASP_[i])    v = w[(y*64 + (s-2)*32 + k)*9 + A2_[i]];
    else if (i == 0)      v = s2[y*64 + (s-2)*32 + k];
    g_WinB[idx] = f2bf(v);
  } else if (idx < 458752) {                // g_WoutB
    int t2 = idx - 262144;
    int j = t2&7, l=(t2>>3)&63, nt=(t2>>9)&3, rest=t2>>11;
    int s = rest % 6, i = rest / 6;
    int y = nt*16 + (l&15), k = ((l>>4)&3)*8 + j;
    float v = 0.f;
    if (s < 2)                    v = wO[(y*64 + s*32 + k)*9 + G_[i]];
    else if (s < 4 && HASP_[i])   v = wO[(y*64 + (s-2)*32 + k)*9 + A2_[i]];
    else if (i == 0)              v = s2O[y*128 + (s-2)*32 + k];
    g_WoutB[t2] = f2bf(v);
  } else if (idx < 471040) {                // g_WsB
    int t3 = idx - 458752;
    int j = t3&7, l=(t3>>3)&63, nt=(t3>>9)&3, s=t3>>11;
    int ys = nt*16 + (l&15), k = ((l>>4)&3)*8 + j;
    float v = (s < 2) ? mv2s[ys*64 + s*32 + k] : s2s[ys*128 + (s-2)*32 + k];
    g_WsB[t3] = f2bf(v);
  }
}

// ---------------- fused main kernel ----------------
// 256 threads = 4 waves, 16 tokens/block.
// wave roles P1/P2: (g = wv>>1 : 0=gp(L,R), 1=join(JL,JR)) x (h = wv&1 : y-half)
// wave roles P3: nt = wv (16-col tile of the 64 output channels)
__global__ __launch_bounds__(256, 2) void fused(
    const float* __restrict__ mv1, const float* __restrict__ mv2,
    const float* __restrict__ sc1, const float* __restrict__ sc2,
    const float* __restrict__ refmv, const float* __restrict__ bias,
    float* __restrict__ out)
{
  __shared__ unsigned int s_mv[8192];   // [(i*16+t)*32 + dw], 32KB; aliased as hidden later
  __shared__ unsigned int s_sc[1024];   // [t*64 + dw], 4KB  (s_cat bf16, swizzled)
  __shared__ float s_ref[16];

  const int tid  = threadIdx.x;
  const int lane = tid & 63, wv = tid >> 6;
  const int tr   = lane & 15, u = lane >> 4;
  const int g    = wv >> 1,  h = wv & 1;
  const size_t tok0 = (size_t)blockIdx.x * 16;

  // ---- staging helpers ----
  auto stage_mv = [&](const float* __restrict__ src){
    #pragma unroll
    for (int it=0; it<2; ++it){
      int flat = tid + it*256;
      int x2 = flat & 31, t = flat >> 5;
      const float* b0 = src + (tok0+t)*1024 + x2*32;
      float4 A[4], B[4];
      #pragma unroll
      for (int q=0;q<4;q++){
        A[q] = *(const float4*)(b0 + q*4);
        B[q] = *(const float4*)(b0 + 16 + q*4);
      }
      unsigned int* dst = &s_mv[t*32 + (x2 ^ ((t&7)<<2))];
      #pragma unroll
      for (int q=0;q<4;q++){
        #pragma unroll
        for (int e=0;e<4;e++){
          int i = q*4 + e;
          dst[i*512] = pack2(((const float*)&A[q])[e], ((const float*)&B[q])[e]);
        }
      }
    }
  };

  // ---- A-fragment readers (swizzle-consistent with staging) ----
  auto afrag = [&](int comp, int sh)->s16x8 {
    const unsigned short* p = (const unsigned short*)s_mv;
    return *(const s16x8*)&p[(comp*16 + tr)*64 + (((sh*4 + u) ^ (tr&7)) << 3)];
  };
  auto scfrag = [&](int ss)->s16x8 {
    const unsigned short* p = (const unsigned short*)s_sc;
    return *(const s16x8*)&p[tr*128 + (((ss*4 + u) ^ (tr&7)) << 3)];
  };
  auto bfragIn = [&](int m,int i,int s)->s16x8 {
    return *(const s16x8*)&g_WinB[((((m*16+i)*4+s)*2+h)*512) + lane*8];
  };
  auto bfragOut = [&](int i,int s,int nt)->s16x8 {
    return *(const s16x8*)&g_WoutB[(((i*6+s)*4+nt)*512) + lane*8];
  };
  auto bfragS = [&](int s,int nt)->s16x8 {
    return *(const s16x8*)&g_WsB[((s*4+nt)*512) + lane*8];
  };

  // ---- P0: stage scalars, ref, mv1 ----
  #pragma unroll
  for (int it=0; it<4; ++it){
    int flat = tid + it*256;
    int cp = flat & 63, t = flat >> 6;
    float a, b;
    if (cp < 32){ const float* p = sc1 + (tok0+t)*64 + cp*2;      a=p[0]; b=p[1]; }
    else        { const float* p = sc2 + (tok0+t)*64 + (cp-32)*2; a=p[0]; b=p[1]; }
    s_sc[t*64 + (cp ^ ((t&7)<<2))] = pack2(a,b);
  }
  if (tid < 16) s_ref[tid] = refmv[(tok0+tid)*16 + 15];
  stage_mv(mv1);
  __syncthreads();

  // ---- P1a: maps from mv1 (gp-wave: L ; join-wave: JL); sc1 folded as K-steps ----
  f32x4 accA[16], accB[16];
  #pragma unroll
  for (int i=0;i<16;i++){ accA[i] = (f32x4)0.f; accB[i] = (f32x4)0.f; }

  {
    const int m = (g==0) ? 0 : 2;
    #pragma unroll
    for (int i=0;i<16;i++){
      accA[i] = __builtin_amdgcn_mfma_f32_16x16x32_bf16(afrag(i,0), bfragIn(m,i,0), accA[i],0,0,0);
      accA[i] = __builtin_amdgcn_mfma_f32_16x16x32_bf16(afrag(i,1), bfragIn(m,i,1), accA[i],0,0,0);
      if (HASP_[i]){
        accA[i] = __builtin_amdgcn_mfma_f32_16x16x32_bf16(afrag(SRC_[i],0), bfragIn(m,i,2), accA[i],0,0,0);
        accA[i] = __builtin_amdgcn_mfma_f32_16x16x32_bf16(afrag(SRC_[i],1), bfragIn(m,i,3), accA[i],0,0,0);
      } else if (i==0){
        accA[i] = __builtin_amdgcn_mfma_f32_16x16x32_bf16(scfrag(0), bfragIn(m,0,2), accA[i],0,0,0);
        accA[i] = __builtin_amdgcn_mfma_f32_16x16x32_bf16(scfrag(1), bfragIn(m,0,3), accA[i],0,0,0);
      }
    }
  }
  __syncthreads();

  // ---- P1b: restage with mv2 ----
  stage_mv(mv2);
  __syncthreads();

  // ---- P1c: maps from mv2 (gp-wave: R ; join-wave: JR); sc2 folded ----
  {
    const int m = (g==0) ? 1 : 3;
    #pragma unroll
    for (int i=0;i<16;i++){
      accB[i] = __builtin_amdgcn_mfma_f32_16x16x32_bf16(afrag(i,0), bfragIn(m,i,0), accB[i],0,0,0);
      accB[i] = __builtin_amdgcn_mfma_f32_16x16x32_bf16(afrag(i,1), bfragIn(m,i,1), accB[i],0,0,0);
      if (HASP_[i]){
        accB[i] = __builtin_amdgcn_mfma_f32_16x16x32_bf16(afrag(SRC_[i],0), bfragIn(m,i,2), accB[i],0,0,0);
        accB[i] = __builtin_amdgcn_mfma_f32_16x16x32_bf16(afrag(SRC_[i],1), bfragIn(m,i,3), accB[i],0,0,0);
      } else if (i==0){
        accB[i] = __builtin_amdgcn_mfma_f32_16x16x32_bf16(scfrag(2), bfragIn(m,0,2), accB[i],0,0,0);
        accB[i] = __builtin_amdgcn_mfma_f32_16x16x32_bf16(scfrag(3), bfragIn(m,0,3), accB[i],0,0,0);
      }
    }
  }
  __syncthreads();

  // ---- P2: Cayley GP / join, fully in registers; write hidden (aliases s_mv) ----
  {
    unsigned short* hidp = (unsigned short*)s_mv;
    if (g == 0){
      constexpr GTab CAY = mk_cayley();
      #pragma unroll
      for (int r=0;r<4;r++){
        const int t = u*4 + r;
        float L[16], R[16];
        #pragma unroll
        for (int j2=0;j2<16;j2++){ L[j2]=accA[j2][r]; R[j2]=accB[j2][r]; }
        const int c = h*16 + tr;
        #pragma unroll
        for (int i=0;i<16;i++){
          float a = 0.f;
          #pragma unroll
          for (int e=0;e<CAY.cnt[i];e++){
            float p = L[(int)CAY.jj[i][e]] * R[(int)CAY.kk[i][e]];
            a = (CAY.ss[i][e] > 0) ? (a + p) : (a - p);
          }
          hidp[(i*16 + t)*64 + (c ^ ((t&7)<<3))] = f2bf(a);
        }
      }
    } else {
      constexpr GTab JNT = mk_join();
      #pragma unroll
      for (int r=0;r<4;r++){
        const int t = u*4 + r;
        float rv = s_ref[t];
        float L[16], R[16];
        #pragma unroll
        for (int j2=0;j2<16;j2++){ L[j2]=accA[j2][r]; R[j2]=accB[j2][r]; }
        const int c = 32 + h*16 + tr;
        #pragma unroll
        for (int i=0;i<16;i++){
          float a = 0.f;
          #pragma unroll
          for (int e=0;e<JNT.cnt[i];e++){
            float p = L[(int)JNT.jj[i][e]] * R[(int)JNT.kk[i][e]];
            a = (JNT.ss[i][e] > 0) ? (a + p) : (a - p);
          }
          hidp[(i*16 + t)*64 + (c ^ ((t&7)<<3))] = f2bf(a * rv);
        }
      }
    }
  }
  __syncthreads();

  // ---- P3: output equi-linear + scalar head via MFMA; wave = n-tile ----
  {
    const int nt = wv;
    f32x4 accO[16]; f32x4 accS = (f32x4)0.f;
    #pragma unroll
    for (int i=0;i<16;i++) accO[i] = (f32x4)0.f;

    s16x8 h00 = afrag(0,0), h01 = afrag(0,1);   // hidden comp 0 (shared with out_s)

    #pragma unroll
    for (int i=0;i<16;i++){
      s16x8 a0 = (i==0) ? h00 : afrag(i,0);
      s16x8 a1 = (i==0) ? h01 : afrag(i,1);
      accO[i] = __builtin_amdgcn_mfma_f32_16x16x32_bf16(a0, bfragOut(i,0,nt), accO[i],0,0,0);
      accO[i] = __builtin_amdgcn_mfma_f32_16x16x32_bf16(a1, bfragOut(i,1,nt), accO[i],0,0,0);
      if (HASP_[i]){
        accO[i] = __builtin_amdgcn_mfma_f32_16x16x32_bf16(afrag(SRC_[i],0), bfragOut(i,2,nt), accO[i],0,0,0);
        accO[i] = __builtin_amdgcn_mfma_f32_16x16x32_bf16(afrag(SRC_[i],1), bfragOut(i,3,nt), accO[i],0,0,0);
      } else if (i==0){
        #pragma unroll
        for (int ss=0;ss<4;ss++)
          accO[0] = __builtin_amdgcn_mfma_f32_16x16x32_bf16(scfrag(ss), bfragOut(0,2+ss,nt), accO[0],0,0,0);
      }
    }
    // scalar head: bias + mv2s·hidden[:,0] + s2s·s_cat
    accS = __builtin_amdgcn_mfma_f32_16x16x32_bf16(h00, bfragS(0,nt), accS,0,0,0);
    accS = __builtin_amdgcn_mfma_f32_16x16x32_bf16(h01, bfragS(1,nt), accS,0,0,0);
    #pragma unroll
    for (int ss=0;ss<4;ss++)
      accS = __builtin_amdgcn_mfma_f32_16x16x32_bf16(scfrag(ss), bfragS(2+ss,nt), accS,0,0,0);

    const int y = nt*16 + tr;
    const float bv = bias[y];
    #pragma unroll
    for (int r=0;r<4;r++){
      const int t = u*4 + r;
      out[OUT_S_OFF + (tok0+t)*64 + y] = accS[r] + bv;
      float* ob = out + (tok0+t)*1024 + y*16;
      #pragma unroll
      for (int iq=0;iq<4;iq++){
        f32x4 v = { accO[iq*4+0][r], accO[iq*4+1][r], accO[iq*4+2][r], accO[iq*4+3][r] };
        *(f32x4*)(ob + iq*4) = v;
      }
    }
  }
}

extern "C" void kernel_launch(void* const* d_in, const int* in_sizes, int n_in,
                              void* d_out, int out_size, void* d_ws, size_t ws_size,
                              hipStream_t stream) {
  const float* mv1   = (const float*)d_in[0];
  const float* mv2   = (const float*)d_in[1];
  const float* sc1   = (const float*)d_in[2];
  const float* sc2   = (const float*)d_in[3];
  const float* refmv = (const float*)d_in[4];
  const float* wL    = (const float*)d_in[5];
  const float* s2L   = (const float*)d_in[6];
  const float* wR    = (const float*)d_in[7];
  const float* s2R   = (const float*)d_in[8];
  const float* wJL   = (const float*)d_in[9];
  const float* s2JL  = (const float*)d_in[10];
  const float* wJR   = (const float*)d_in[11];
  const float* s2JR  = (const float*)d_in[12];
  const float* wO    = (const float*)d_in[13];
  const float* s2O   = (const float*)d_in[14];
  const float* mv2s  = (const float*)d_in[15];
  const float* s2s   = (const float*)d_in[16];
  const float* bias  = (const float*)d_in[17];
  float* out = (float*)d_out;

  prepack<<<1840, 256, 0, stream>>>(wL,wR,wJL,wJR,wO, s2L,s2R,s2JL,s2JR, s2O, mv2s, s2s);
  fused<<<2048, 256, 0, stream>>>(mv1, mv2, sc1, sc2, refmv, bias, out);
}